// Round 1
// baseline (2378.481 us; speedup 1.0000x reference)
//
#include <hip/hip_runtime.h>
#include <stdint.h>

#define T_SEQ 2048
#define C_DIM 4096
#define NHEAD 32
#define NKV 8
#define HD 128
#define HIDDEN 11008

typedef float f32x4 __attribute__((ext_vector_type(4)));
typedef __bf16 bf16x8 __attribute__((ext_vector_type(8)));
typedef __attribute__((address_space(1))) const void* gptr_t;
typedef __attribute__((address_space(3))) void* lptr_t;

__device__ __forceinline__ unsigned short f2bf(float f) {
  unsigned u = __float_as_uint(f);
  u += 0x7fffu + ((u >> 16) & 1u);
  return (unsigned short)(u >> 16);
}
__device__ __forceinline__ float bf2f(unsigned short h) {
  return __uint_as_float(((unsigned)h) << 16);
}

// ---------------------------------------------------------------------------
// Generic bf16 GEMM: C[M,N] = A[M,K] @ B[N,K]^T (+ optional fp32 residual)
// m97-style: 128x128 tile, BK=64, 4 waves, 4x4 MFMA 16x16x32 per wave,
// global_load_lds width=16 staging. Requires M%128==0, N%128==0, K%64==0.
// Batched over blockIdx.z with element strides; B stride applies to (z>>bzShift).
// ---------------------------------------------------------------------------
template <typename OutT, bool RESID>
__global__ __launch_bounds__(256) void gemm_bt(
    const unsigned short* A, int lda, long sAz,
    const unsigned short* B, int ldb, long sBz, int bzShift,
    OutT* C, int ldc, long sCz,
    const float* R,
    int M, int N, int K)
{
  const int z = blockIdx.z;
  A += (long)z * sAz;
  B += (long)(z >> bzShift) * sBz;
  C += (long)z * sCz;
  const float* Rz = R + (long)z * sCz;

  __shared__ unsigned short lA[128 * 64];
  __shared__ unsigned short lB[128 * 64];

  const int t    = threadIdx.x;
  const int lane = t & 63;
  const int srow = t >> 3;        // 0..31
  const int scol = (t & 7) << 3;  // 0,8,..,56
  const int wave = t >> 6;
  const int wr   = (wave >> 1) << 6;
  const int wc   = (wave & 1) << 6;
  const int m16  = lane & 15;
  const int quad = lane >> 4;

  const long tileM = (long)blockIdx.y * 128;
  const long tileN = (long)blockIdx.x * 128;

  f32x4 acc[4][4] = {};

  const unsigned short* Abase = A + (tileM + srow) * lda + scol;
  const unsigned short* Bbase = B + (tileN + srow) * ldb + scol;

  for (int k0 = 0; k0 < K; k0 += 64) {
#pragma unroll
    for (int s = 0; s < 4; ++s) {
      const unsigned short* ga = Abase + (long)(s * 32) * lda + k0;
      const unsigned short* gb = Bbase + (long)(s * 32) * ldb + k0;
      unsigned short* la = &lA[(s * 32 + srow) * 64 + scol];
      unsigned short* lb = &lB[(s * 32 + srow) * 64 + scol];
      __builtin_amdgcn_global_load_lds((gptr_t)ga, (lptr_t)la, 16, 0, 0);
      __builtin_amdgcn_global_load_lds((gptr_t)gb, (lptr_t)lb, 16, 0, 0);
    }
    __syncthreads();
#pragma unroll
    for (int kk = 0; kk < 64; kk += 32) {
      bf16x8 af[4], bfr[4];
#pragma unroll
      for (int i = 0; i < 4; ++i)
        af[i] = *(const bf16x8*)&lA[(wr + i * 16 + m16) * 64 + kk + quad * 8];
#pragma unroll
      for (int j = 0; j < 4; ++j)
        bfr[j] = *(const bf16x8*)&lB[(wc + j * 16 + m16) * 64 + kk + quad * 8];
#pragma unroll
      for (int i = 0; i < 4; ++i)
#pragma unroll
        for (int j = 0; j < 4; ++j)
          acc[i][j] = __builtin_amdgcn_mfma_f32_16x16x32_bf16(af[i], bfr[j], acc[i][j], 0, 0, 0);
    }
    __syncthreads();
  }

  // C/D layout (verified m89/m91): col = lane&15, row = (lane>>4)*4 + reg
#pragma unroll
  for (int i = 0; i < 4; ++i) {
#pragma unroll
    for (int j = 0; j < 4; ++j) {
      const long row = tileM + wr + i * 16 + quad * 4;
      const long col = tileN + wc + j * 16 + m16;
#pragma unroll
      for (int r = 0; r < 4; ++r) {
        const long off = (row + r) * (long)ldc + col;
        float v = acc[i][j][r];
        if constexpr (RESID) v += Rz[off];
        if constexpr (sizeof(OutT) == 2) C[off] = f2bf(v);
        else                             C[off] = v;
      }
    }
  }
}

// ---------------------------------------------------------------------------
__global__ __launch_bounds__(256) void rmsnorm_kernel(
    const float* __restrict__ x, const float* __restrict__ w,
    unsigned short* __restrict__ out)
{
  const int row = blockIdx.x;
  const int t = threadIdx.x;
  const float4* xr = (const float4*)(x + (long)row * C_DIM);
  float4 xv[4];
  float s = 0.f;
#pragma unroll
  for (int i = 0; i < 4; ++i) {
    float4 a = xr[t * 4 + i];
    xv[i] = a;
    s += a.x * a.x + a.y * a.y + a.z * a.z + a.w * a.w;
  }
#pragma unroll
  for (int off = 32; off > 0; off >>= 1) s += __shfl_down(s, off);
  __shared__ float red[4];
  if ((t & 63) == 0) red[t >> 6] = s;
  __syncthreads();
  const float inv = rsqrtf((red[0] + red[1] + red[2] + red[3]) * (1.f / C_DIM) + 1e-6f);
  const float4* wr4 = (const float4*)w;
  ushort4* o = (ushort4*)(out + (long)row * C_DIM);
#pragma unroll
  for (int i = 0; i < 4; ++i) {
    float4 a = xv[i];
    float4 ww = wr4[t * 4 + i];
    ushort4 r;
    r.x = f2bf(a.x * inv * ww.x); r.y = f2bf(a.y * inv * ww.y);
    r.z = f2bf(a.z * inv * ww.z); r.w = f2bf(a.w * inv * ww.w);
    o[t * 4 + i] = r;
  }
}

// fp32 -> bf16, 4 elements/thread, grid must be exact (n % 1024 == 0)
__global__ __launch_bounds__(256) void cvt_kernel(
    const float* __restrict__ in, unsigned short* __restrict__ out)
{
  const long i = (long)blockIdx.x * 256 + threadIdx.x;
  float4 f = ((const float4*)in)[i];
  ushort4 r;
  r.x = f2bf(f.x); r.y = f2bf(f.y); r.z = f2bf(f.z); r.w = f2bf(f.w);
  ((ushort4*)out)[i] = r;
}

template <int NHd>
__global__ __launch_bounds__(256) void rope_kernel(
    unsigned short* tq, const float* __restrict__ cp, const float* __restrict__ sp)
{
  constexpr int SH = (NHd == 32) ? 5 : 3;
  const long idx = (long)blockIdx.x * 256 + threadIdx.x;  // over T*NHd*64
  const int i = (int)(idx & 63);
  const long rest = idx >> 6;
  const int h = (int)(rest & (NHd - 1));
  const int t = (int)(rest >> SH);
  const long base = (((long)t * NHd + h) << 7) + 2 * i;
  const float re = bf2f(tq[base]);
  const float im = bf2f(tq[base + 1]);
  const float c = cp[t * 64 + i];
  const float s = sp[t * 64 + i];
  tq[base]     = f2bf(re * c - im * s);
  tq[base + 1] = f2bf(re * s + im * c);
}

// vt[kvd][t] = v[t][kvd]   (kvd in [0,1024), t in [0,2048))
__global__ __launch_bounds__(256) void transpose_v(
    const unsigned short* __restrict__ v, unsigned short* __restrict__ vt)
{
  const long idx = (long)blockIdx.x * 256 + threadIdx.x;
  const int t = (int)(idx & 2047);
  const int kvd = (int)(idx >> 11);
  vt[idx] = v[(long)t * 1024 + kvd];
}

// In-place causal softmax: fp32 row (len 2048) -> bf16 probs over same bytes.
// Mask folded in analytically (k<=q), scale = 1/sqrt(128).
__global__ __launch_bounds__(256) void softmax_kernel(float* scores)
{
  const int q = blockIdx.x;
  const long z = blockIdx.y;
  float* row = scores + (z * T_SEQ + q) * (long)T_SEQ;
  unsigned short* orow = (unsigned short*)(scores + z * (long)T_SEQ * T_SEQ) + (long)q * 2 * T_SEQ;
  const int t = threadIdx.x;
  const int base = t * 8;
  float4 a = ((const float4*)row)[t * 2];
  float4 b = ((const float4*)row)[t * 2 + 1];
  float v[8] = {a.x, a.y, a.z, a.w, b.x, b.y, b.z, b.w};
  const float scale = 0.08838834764831845f;
  float mx = -INFINITY;
#pragma unroll
  for (int j = 0; j < 8; ++j) {
    v[j] = (base + j <= q) ? v[j] * scale : -INFINITY;
    mx = fmaxf(mx, v[j]);
  }
#pragma unroll
  for (int off = 32; off > 0; off >>= 1) mx = fmaxf(mx, __shfl_down(mx, off));
  __shared__ float redm[4], reds[4];
  if ((t & 63) == 0) redm[t >> 6] = mx;
  __syncthreads();
  mx = fmaxf(fmaxf(redm[0], redm[1]), fmaxf(redm[2], redm[3]));
  float s = 0.f;
#pragma unroll
  for (int j = 0; j < 8; ++j) {
    float e = (base + j <= q) ? __expf(v[j] - mx) : 0.f;
    v[j] = e;
    s += e;
  }
#pragma unroll
  for (int off = 32; off > 0; off >>= 1) s += __shfl_down(s, off);
  if ((t & 63) == 0) reds[t >> 6] = s;
  __syncthreads();
  s = reds[0] + reds[1] + reds[2] + reds[3];
  const float inv = 1.f / s;
  ushort4 o0, o1;
  o0.x = f2bf(v[0] * inv); o0.y = f2bf(v[1] * inv);
  o0.z = f2bf(v[2] * inv); o0.w = f2bf(v[3] * inv);
  o1.x = f2bf(v[4] * inv); o1.y = f2bf(v[5] * inv);
  o1.z = f2bf(v[6] * inv); o1.w = f2bf(v[7] * inv);
  ((ushort4*)orow)[t * 2]     = o0;
  ((ushort4*)orow)[t * 2 + 1] = o1;
}

// h = silu(g1) * g3, 4 elements/thread
__global__ __launch_bounds__(256) void silu_mul_kernel(
    const unsigned short* __restrict__ g1, const unsigned short* __restrict__ g3,
    unsigned short* __restrict__ h)
{
  const long i = (long)blockIdx.x * 256 + threadIdx.x;
  ushort4 a4 = ((const ushort4*)g1)[i];
  ushort4 b4 = ((const ushort4*)g3)[i];
  ushort4 r;
  { float a = bf2f(a4.x), b = bf2f(b4.x); r.x = f2bf(a / (1.f + __expf(-a)) * b); }
  { float a = bf2f(a4.y), b = bf2f(b4.y); r.y = f2bf(a / (1.f + __expf(-a)) * b); }
  { float a = bf2f(a4.z), b = bf2f(b4.z); r.z = f2bf(a / (1.f + __expf(-a)) * b); }
  { float a = bf2f(a4.w), b = bf2f(b4.w); r.w = f2bf(a / (1.f + __expf(-a)) * b); }
  ((ushort4*)h)[i] = r;
}

// ---------------------------------------------------------------------------
extern "C" void kernel_launch(void* const* d_in, const int* in_sizes, int n_in,
                              void* d_out, int out_size, void* d_ws, size_t ws_size,
                              hipStream_t stream) {
  const float* x    = (const float*)d_in[0];
  // d_in[1] = start_pos (0); d_in[4] = mask (causal, folded analytically)
  const float* fcos = (const float*)d_in[2];
  const float* fsin = (const float*)d_in[3];
  const float* wq   = (const float*)d_in[5];
  const float* wk   = (const float*)d_in[6];
  const float* wv   = (const float*)d_in[7];
  const float* wo   = (const float*)d_in[8];
  const float* w1   = (const float*)d_in[9];
  const float* w2   = (const float*)d_in[10];
  const float* w3   = (const float*)d_in[11];
  const float* ln1  = (const float*)d_in[12];
  const float* ln2  = (const float*)d_in[13];
  float* out = (float*)d_out;  // also serves as x_mid (attention residual output)

  // workspace layout (~305 MB)
  char* p = (char*)d_ws;
  auto alloc = [&](size_t bytes) { char* r = p; p += (bytes + 255) & ~(size_t)255; return r; };
  unsigned short* Wb   = (unsigned short*)alloc((size_t)HIDDEN * C_DIM * 2);     // 90.2 MB, reused per-GEMM
  unsigned short* xn   = (unsigned short*)alloc((size_t)T_SEQ * C_DIM * 2);
  unsigned short* qb   = (unsigned short*)alloc((size_t)T_SEQ * C_DIM * 2);
  unsigned short* kb   = (unsigned short*)alloc((size_t)T_SEQ * 1024 * 2);
  unsigned short* vb   = (unsigned short*)alloc((size_t)T_SEQ * 1024 * 2);
  unsigned short* vt   = (unsigned short*)alloc((size_t)T_SEQ * 1024 * 2);
  unsigned short* attn = (unsigned short*)alloc((size_t)T_SEQ * C_DIM * 2);
  const size_t scoresB = (size_t)8 * T_SEQ * T_SEQ * 4;                     // 134 MB
  const size_t ffnB    = (size_t)T_SEQ * C_DIM * 2 + 3ULL * T_SEQ * HIDDEN * 2;  // 152 MB
  char* regC = alloc(scoresB > ffnB ? scoresB : ffnB);
  float* scores = (float*)regC;  // attention phase
  unsigned short* xn2 = (unsigned short*)regC;  // FFN phase (after attention done)
  unsigned short* g1  = (unsigned short*)(regC + (size_t)T_SEQ * C_DIM * 2);
  unsigned short* g3  = (unsigned short*)(regC + (size_t)T_SEQ * C_DIM * 2 + (size_t)T_SEQ * HIDDEN * 2);
  unsigned short* hb  = (unsigned short*)(regC + (size_t)T_SEQ * C_DIM * 2 + 2ULL * T_SEQ * HIDDEN * 2);

  // 1) xn = rmsnorm(x) in bf16
  rmsnorm_kernel<<<T_SEQ, 256, 0, stream>>>(x, ln1, xn);

  // 2) q/k/v projections (weights converted to bf16 into Wb first)
  cvt_kernel<<<(C_DIM * C_DIM) / 1024, 256, 0, stream>>>(wq, Wb);
  gemm_bt<unsigned short, false><<<dim3(C_DIM / 128, T_SEQ / 128, 1), 256, 0, stream>>>(
      xn, C_DIM, 0, Wb, C_DIM, 0, 0, qb, C_DIM, 0, nullptr, T_SEQ, C_DIM, C_DIM);
  cvt_kernel<<<(1024 * C_DIM) / 1024, 256, 0, stream>>>(wk, Wb);
  gemm_bt<unsigned short, false><<<dim3(1024 / 128, T_SEQ / 128, 1), 256, 0, stream>>>(
      xn, C_DIM, 0, Wb, C_DIM, 0, 0, kb, 1024, 0, nullptr, T_SEQ, 1024, C_DIM);
  cvt_kernel<<<(1024 * C_DIM) / 1024, 256, 0, stream>>>(wv, Wb);
  gemm_bt<unsigned short, false><<<dim3(1024 / 128, T_SEQ / 128, 1), 256, 0, stream>>>(
      xn, C_DIM, 0, Wb, C_DIM, 0, 0, vb, 1024, 0, nullptr, T_SEQ, 1024, C_DIM);

  // 3) RoPE on q and k; transpose v per kv-head
  rope_kernel<NHEAD><<<(T_SEQ * NHEAD * 64) / 256, 256, 0, stream>>>(qb, fcos, fsin);
  rope_kernel<NKV><<<(T_SEQ * NKV * 64) / 256, 256, 0, stream>>>(kb, fcos, fsin);
  transpose_v<<<(T_SEQ * 1024) / 256, 256, 0, stream>>>(vb, vt);

  // 4) attention, 4 chunks of 8 heads (heads 8c..8c+7 -> kv heads 2c + z/4)
  for (int c = 0; c < 4; ++c) {
    gemm_bt<float, false><<<dim3(T_SEQ / 128, T_SEQ / 128, 8), 256, 0, stream>>>(
        qb + c * 1024, C_DIM, 128,
        kb + c * 256, 1024, 128, 2,
        scores, T_SEQ, (long)T_SEQ * T_SEQ, nullptr,
        T_SEQ, T_SEQ, HD);
    softmax_kernel<<<dim3(T_SEQ, 8), 256, 0, stream>>>(scores);
    gemm_bt<unsigned short, false><<<dim3(1, T_SEQ / 128, 8), 256, 0, stream>>>(
        (unsigned short*)scores, 2 * T_SEQ, (long)T_SEQ * 2 * T_SEQ,
        vt + (size_t)c * 2 * HD * T_SEQ, T_SEQ, (long)HD * T_SEQ, 2,
        attn + c * 1024, C_DIM, 128, nullptr,
        T_SEQ, HD, T_SEQ);
  }

  // 5) out = x + attn @ wo^T  (fp32, into d_out == x_mid)
  cvt_kernel<<<(C_DIM * C_DIM) / 1024, 256, 0, stream>>>(wo, Wb);
  gemm_bt<float, true><<<dim3(C_DIM / 128, T_SEQ / 128, 1), 256, 0, stream>>>(
      attn, C_DIM, 0, Wb, C_DIM, 0, 0, out, C_DIM, 0, x, T_SEQ, C_DIM, C_DIM);

  // 6) FFN: xn2 = rmsnorm(out); h = silu(xn2@w1^T) * (xn2@w3^T); out += h@w2^T
  rmsnorm_kernel<<<T_SEQ, 256, 0, stream>>>(out, ln2, xn2);
  cvt_kernel<<<((size_t)HIDDEN * C_DIM) / 1024, 256, 0, stream>>>(w1, Wb);
  gemm_bt<unsigned short, false><<<dim3(HIDDEN / 128, T_SEQ / 128, 1), 256, 0, stream>>>(
      xn2, C_DIM, 0, Wb, C_DIM, 0, 0, g1, HIDDEN, 0, nullptr, T_SEQ, HIDDEN, C_DIM);
  cvt_kernel<<<((size_t)HIDDEN * C_DIM) / 1024, 256, 0, stream>>>(w3, Wb);
  gemm_bt<unsigned short, false><<<dim3(HIDDEN / 128, T_SEQ / 128, 1), 256, 0, stream>>>(
      xn2, C_DIM, 0, Wb, C_DIM, 0, 0, g3, HIDDEN, 0, nullptr, T_SEQ, HIDDEN, C_DIM);
  silu_mul_kernel<<<((size_t)T_SEQ * HIDDEN) / 1024, 256, 0, stream>>>(g1, g3, hb);
  cvt_kernel<<<((size_t)C_DIM * HIDDEN) / 1024, 256, 0, stream>>>(w2, Wb);
  gemm_bt<float, true><<<dim3(C_DIM / 128, T_SEQ / 128, 1), 256, 0, stream>>>(
      hb, HIDDEN, 0, Wb, HIDDEN, 0, 0, out, C_DIM, 0, out, T_SEQ, C_DIM, HIDDEN);
}

// Round 2
// 2137.666 us; speedup vs baseline: 1.1127x; 1.1127x over previous
//
#include <hip/hip_runtime.h>
#include <stdint.h>

#define T_SEQ 2048
#define C_DIM 4096
#define NHEAD 32
#define NKV 8
#define HD 128
#define HIDDEN 11008

typedef float f32x4 __attribute__((ext_vector_type(4)));
typedef __bf16 bf16x8 __attribute__((ext_vector_type(8)));
typedef __attribute__((address_space(1))) const void* gptr_t;
typedef __attribute__((address_space(3))) void* lptr_t;

__device__ __forceinline__ unsigned short f2bf(float f) {
  unsigned u = __float_as_uint(f);
  u += 0x7fffu + ((u >> 16) & 1u);
  return (unsigned short)(u >> 16);
}
__device__ __forceinline__ float bf2f(unsigned short h) {
  return __uint_as_float(((unsigned)h) << 16);
}

// ---------------------------------------------------------------------------
// Generic bf16 GEMM: C[M,N] = A[M,K] @ B[N,K]^T (+ optional fp32 residual)
// m97-style: 128x128 tile, BK=64, 4 waves, 4x4 MFMA 16x16x32 per wave,
// global_load_lds width=16 staging.
// LDS XOR swizzle: 16-B chunk p of row r stores global chunk p^(r&7) so that
// quad-wise ds_read_b128 (row = lane&15) spreads across all 8 bank groups
// (2-way aliasing only, which is free). Swizzle is applied on the GLOBAL
// source address at staging time (LDS dest of global_load_lds is fixed at
// base + lane*16 and cannot be scattered).
// Batched over blockIdx.z with element strides; B stride applies to (z>>bzShift).
// ---------------------------------------------------------------------------
template <typename OutT, bool RESID>
__global__ __launch_bounds__(256) void gemm_bt(
    const unsigned short* A, int lda, long sAz,
    const unsigned short* B, int ldb, long sBz, int bzShift,
    OutT* C, int ldc, long sCz,
    const float* R,
    int M, int N, int K)
{
  const int z = blockIdx.z;
  A += (long)z * sAz;
  B += (long)(z >> bzShift) * sBz;
  C += (long)z * sCz;
  const float* Rz = R + (long)z * sCz;

  __shared__ unsigned short lA[128 * 64];
  __shared__ unsigned short lB[128 * 64];

  const int t    = threadIdx.x;
  const int lane = t & 63;
  const int srow = t >> 3;                          // 0..31
  const int scolL = (t & 7) << 3;                   // LDS chunk position (fixed by HW)
  const int scolG = (((t & 7) ^ (srow & 7)) << 3);  // swizzled global chunk
  const int wave = t >> 6;
  const int wr   = (wave >> 1) << 6;
  const int wc   = (wave & 1) << 6;
  const int m16  = lane & 15;
  const int quad = lane >> 4;
  const int rl   = lane & 7;                        // row&7 for fragment rows

  const long tileM = (long)blockIdx.y * 128;
  const long tileN = (long)blockIdx.x * 128;

  f32x4 acc[4][4] = {};

  const unsigned short* Abase = A + (tileM + srow) * lda + scolG;
  const unsigned short* Bbase = B + (tileN + srow) * ldb + scolG;

  for (int k0 = 0; k0 < K; k0 += 64) {
#pragma unroll
    for (int s = 0; s < 4; ++s) {
      const unsigned short* ga = Abase + (long)(s * 32) * lda + k0;
      const unsigned short* gb = Bbase + (long)(s * 32) * ldb + k0;
      unsigned short* la = &lA[(s * 32 + srow) * 64 + scolL];
      unsigned short* lb = &lB[(s * 32 + srow) * 64 + scolL];
      __builtin_amdgcn_global_load_lds((gptr_t)ga, (lptr_t)la, 16, 0, 0);
      __builtin_amdgcn_global_load_lds((gptr_t)gb, (lptr_t)lb, 16, 0, 0);
    }
    __syncthreads();
#pragma unroll
    for (int kk = 0; kk < 64; kk += 32) {
      const int ca = ((((kk >> 4) >> 1) + quad) ^ rl) << 3;  // ((kk>>3 is 0 or 4) + quad) ^ (row&7)
      bf16x8 af[4], bfr[4];
#pragma unroll
      for (int i = 0; i < 4; ++i)
        af[i] = *(const bf16x8*)&lA[(wr + i * 16 + m16) * 64 + ((((kk >> 3) + quad) ^ rl) << 3)];
#pragma unroll
      for (int j = 0; j < 4; ++j)
        bfr[j] = *(const bf16x8*)&lB[(wc + j * 16 + m16) * 64 + ((((kk >> 3) + quad) ^ rl) << 3)];
      (void)ca;
#pragma unroll
      for (int i = 0; i < 4; ++i)
#pragma unroll
        for (int j = 0; j < 4; ++j)
          acc[i][j] = __builtin_amdgcn_mfma_f32_16x16x32_bf16(af[i], bfr[j], acc[i][j], 0, 0, 0);
    }
    __syncthreads();
  }

  // C/D layout (verified m89/m91): col = lane&15, row = (lane>>4)*4 + reg
#pragma unroll
  for (int i = 0; i < 4; ++i) {
#pragma unroll
    for (int j = 0; j < 4; ++j) {
      const long row = tileM + wr + i * 16 + quad * 4;
      const long col = tileN + wc + j * 16 + m16;
#pragma unroll
      for (int r = 0; r < 4; ++r) {
        const long off = (row + r) * (long)ldc + col;
        float v = acc[i][j][r];
        if constexpr (RESID) v += Rz[off];
        if constexpr (sizeof(OutT) == 2) C[off] = f2bf(v);
        else                             C[off] = v;
      }
    }
  }
}

// ---------------------------------------------------------------------------
__global__ __launch_bounds__(256) void rmsnorm_kernel(
    const float* __restrict__ x, const float* __restrict__ w,
    unsigned short* __restrict__ out)
{
  const int row = blockIdx.x;
  const int t = threadIdx.x;
  const float4* xr = (const float4*)(x + (long)row * C_DIM);
  float4 xv[4];
  float s = 0.f;
#pragma unroll
  for (int i = 0; i < 4; ++i) {
    float4 a = xr[t * 4 + i];
    xv[i] = a;
    s += a.x * a.x + a.y * a.y + a.z * a.z + a.w * a.w;
  }
#pragma unroll
  for (int off = 32; off > 0; off >>= 1) s += __shfl_down(s, off);
  __shared__ float red[4];
  if ((t & 63) == 0) red[t >> 6] = s;
  __syncthreads();
  const float inv = rsqrtf((red[0] + red[1] + red[2] + red[3]) * (1.f / C_DIM) + 1e-6f);
  const float4* wr4 = (const float4*)w;
  ushort4* o = (ushort4*)(out + (long)row * C_DIM);
#pragma unroll
  for (int i = 0; i < 4; ++i) {
    float4 a = xv[i];
    float4 ww = wr4[t * 4 + i];
    ushort4 r;
    r.x = f2bf(a.x * inv * ww.x); r.y = f2bf(a.y * inv * ww.y);
    r.z = f2bf(a.z * inv * ww.z); r.w = f2bf(a.w * inv * ww.w);
    o[t * 4 + i] = r;
  }
}

// fp32 -> bf16, 4 elements/thread, grid must be exact (n % 1024 == 0)
__global__ __launch_bounds__(256) void cvt_kernel(
    const float* __restrict__ in, unsigned short* __restrict__ out)
{
  const long i = (long)blockIdx.x * 256 + threadIdx.x;
  float4 f = ((const float4*)in)[i];
  ushort4 r;
  r.x = f2bf(f.x); r.y = f2bf(f.y); r.z = f2bf(f.z); r.w = f2bf(f.w);
  ((ushort4*)out)[i] = r;
}

template <int NHd>
__global__ __launch_bounds__(256) void rope_kernel(
    unsigned short* tq, const float* __restrict__ cp, const float* __restrict__ sp)
{
  constexpr int SH = (NHd == 32) ? 5 : 3;
  const long idx = (long)blockIdx.x * 256 + threadIdx.x;  // over T*NHd*64
  const int i = (int)(idx & 63);
  const long rest = idx >> 6;
  const int h = (int)(rest & (NHd - 1));
  const int t = (int)(rest >> SH);
  const long base = (((long)t * NHd + h) << 7) + 2 * i;
  const float re = bf2f(tq[base]);
  const float im = bf2f(tq[base + 1]);
  const float c = cp[t * 64 + i];
  const float s = sp[t * 64 + i];
  tq[base]     = f2bf(re * c - im * s);
  tq[base + 1] = f2bf(re * s + im * c);
}

// vt[kvd][t] = v[t][kvd]   (kvd in [0,1024), t in [0,2048))
__global__ __launch_bounds__(256) void transpose_v(
    const unsigned short* __restrict__ v, unsigned short* __restrict__ vt)
{
  const long idx = (long)blockIdx.x * 256 + threadIdx.x;
  const int t = (int)(idx & 2047);
  const int kvd = (int)(idx >> 11);
  vt[idx] = v[(long)t * 1024 + kvd];
}

// In-place causal softmax: fp32 row (len 2048) -> bf16 probs over same bytes.
// Mask folded in analytically (k<=q), scale = 1/sqrt(128).
__global__ __launch_bounds__(256) void softmax_kernel(float* scores)
{
  const int q = blockIdx.x;
  const long z = blockIdx.y;
  float* row = scores + (z * T_SEQ + q) * (long)T_SEQ;
  unsigned short* orow = (unsigned short*)(scores + z * (long)T_SEQ * T_SEQ) + (long)q * 2 * T_SEQ;
  const int t = threadIdx.x;
  const int base = t * 8;
  float4 a = ((const float4*)row)[t * 2];
  float4 b = ((const float4*)row)[t * 2 + 1];
  float v[8] = {a.x, a.y, a.z, a.w, b.x, b.y, b.z, b.w};
  const float scale = 0.08838834764831845f;
  float mx = -INFINITY;
#pragma unroll
  for (int j = 0; j < 8; ++j) {
    v[j] = (base + j <= q) ? v[j] * scale : -INFINITY;
    mx = fmaxf(mx, v[j]);
  }
#pragma unroll
  for (int off = 32; off > 0; off >>= 1) mx = fmaxf(mx, __shfl_down(mx, off));
  __shared__ float redm[4], reds[4];
  if ((t & 63) == 0) redm[t >> 6] = mx;
  __syncthreads();
  mx = fmaxf(fmaxf(redm[0], redm[1]), fmaxf(redm[2], redm[3]));
  float s = 0.f;
#pragma unroll
  for (int j = 0; j < 8; ++j) {
    float e = (base + j <= q) ? __expf(v[j] - mx) : 0.f;
    v[j] = e;
    s += e;
  }
#pragma unroll
  for (int off = 32; off > 0; off >>= 1) s += __shfl_down(s, off);
  if ((t & 63) == 0) reds[t >> 6] = s;
  __syncthreads();
  s = reds[0] + reds[1] + reds[2] + reds[3];
  const float inv = 1.f / s;
  ushort4 o0, o1;
  o0.x = f2bf(v[0] * inv); o0.y = f2bf(v[1] * inv);
  o0.z = f2bf(v[2] * inv); o0.w = f2bf(v[3] * inv);
  o1.x = f2bf(v[4] * inv); o1.y = f2bf(v[5] * inv);
  o1.z = f2bf(v[6] * inv); o1.w = f2bf(v[7] * inv);
  ((ushort4*)orow)[t * 2]     = o0;
  ((ushort4*)orow)[t * 2 + 1] = o1;
}

// h = silu(g1) * g3, 4 elements/thread
__global__ __launch_bounds__(256) void silu_mul_kernel(
    const unsigned short* __restrict__ g1, const unsigned short* __restrict__ g3,
    unsigned short* __restrict__ h)
{
  const long i = (long)blockIdx.x * 256 + threadIdx.x;
  ushort4 a4 = ((const ushort4*)g1)[i];
  ushort4 b4 = ((const ushort4*)g3)[i];
  ushort4 r;
  { float a = bf2f(a4.x), b = bf2f(b4.x); r.x = f2bf(a / (1.f + __expf(-a)) * b); }
  { float a = bf2f(a4.y), b = bf2f(b4.y); r.y = f2bf(a / (1.f + __expf(-a)) * b); }
  { float a = bf2f(a4.z), b = bf2f(b4.z); r.z = f2bf(a / (1.f + __expf(-a)) * b); }
  { float a = bf2f(a4.w), b = bf2f(b4.w); r.w = f2bf(a / (1.f + __expf(-a)) * b); }
  ((ushort4*)h)[i] = r;
}

// ---------------------------------------------------------------------------
extern "C" void kernel_launch(void* const* d_in, const int* in_sizes, int n_in,
                              void* d_out, int out_size, void* d_ws, size_t ws_size,
                              hipStream_t stream) {
  const float* x    = (const float*)d_in[0];
  // d_in[1] = start_pos (0); d_in[4] = mask (causal, folded analytically)
  const float* fcos = (const float*)d_in[2];
  const float* fsin = (const float*)d_in[3];
  const float* wq   = (const float*)d_in[5];
  const float* wk   = (const float*)d_in[6];
  const float* wv   = (const float*)d_in[7];
  const float* wo   = (const float*)d_in[8];
  const float* w1   = (const float*)d_in[9];
  const float* w2   = (const float*)d_in[10];
  const float* w3   = (const float*)d_in[11];
  const float* ln1  = (const float*)d_in[12];
  const float* ln2  = (const float*)d_in[13];
  float* out = (float*)d_out;  // also serves as x_mid (attention residual output)

  // workspace layout (~305 MB)
  char* p = (char*)d_ws;
  auto alloc = [&](size_t bytes) { char* r = p; p += (bytes + 255) & ~(size_t)255; return r; };
  unsigned short* Wb   = (unsigned short*)alloc((size_t)HIDDEN * C_DIM * 2);     // 90.2 MB, reused per-GEMM
  unsigned short* xn   = (unsigned short*)alloc((size_t)T_SEQ * C_DIM * 2);
  unsigned short* qb   = (unsigned short*)alloc((size_t)T_SEQ * C_DIM * 2);
  unsigned short* kb   = (unsigned short*)alloc((size_t)T_SEQ * 1024 * 2);
  unsigned short* vb   = (unsigned short*)alloc((size_t)T_SEQ * 1024 * 2);
  unsigned short* vt   = (unsigned short*)alloc((size_t)T_SEQ * 1024 * 2);
  unsigned short* attn = (unsigned short*)alloc((size_t)T_SEQ * C_DIM * 2);
  const size_t scoresB = (size_t)8 * T_SEQ * T_SEQ * 4;                     // 134 MB
  const size_t ffnB    = (size_t)T_SEQ * C_DIM * 2 + 3ULL * T_SEQ * HIDDEN * 2;  // 152 MB
  char* regC = alloc(scoresB > ffnB ? scoresB : ffnB);
  float* scores = (float*)regC;  // attention phase
  unsigned short* xn2 = (unsigned short*)regC;  // FFN phase (after attention done)
  unsigned short* g1  = (unsigned short*)(regC + (size_t)T_SEQ * C_DIM * 2);
  unsigned short* g3  = (unsigned short*)(regC + (size_t)T_SEQ * C_DIM * 2 + (size_t)T_SEQ * HIDDEN * 2);
  unsigned short* hb  = (unsigned short*)(regC + (size_t)T_SEQ * C_DIM * 2 + 2ULL * T_SEQ * HIDDEN * 2);

  // 1) xn = rmsnorm(x) in bf16
  rmsnorm_kernel<<<T_SEQ, 256, 0, stream>>>(x, ln1, xn);

  // 2) q/k/v projections (weights converted to bf16 into Wb first)
  cvt_kernel<<<(C_DIM * C_DIM) / 1024, 256, 0, stream>>>(wq, Wb);
  gemm_bt<unsigned short, false><<<dim3(C_DIM / 128, T_SEQ / 128, 1), 256, 0, stream>>>(
      xn, C_DIM, 0, Wb, C_DIM, 0, 0, qb, C_DIM, 0, nullptr, T_SEQ, C_DIM, C_DIM);
  cvt_kernel<<<(1024 * C_DIM) / 1024, 256, 0, stream>>>(wk, Wb);
  gemm_bt<unsigned short, false><<<dim3(1024 / 128, T_SEQ / 128, 1), 256, 0, stream>>>(
      xn, C_DIM, 0, Wb, C_DIM, 0, 0, kb, 1024, 0, nullptr, T_SEQ, 1024, C_DIM);
  cvt_kernel<<<(1024 * C_DIM) / 1024, 256, 0, stream>>>(wv, Wb);
  gemm_bt<unsigned short, false><<<dim3(1024 / 128, T_SEQ / 128, 1), 256, 0, stream>>>(
      xn, C_DIM, 0, Wb, C_DIM, 0, 0, vb, 1024, 0, nullptr, T_SEQ, 1024, C_DIM);

  // 3) RoPE on q and k; transpose v per kv-head
  rope_kernel<NHEAD><<<(T_SEQ * NHEAD * 64) / 256, 256, 0, stream>>>(qb, fcos, fsin);
  rope_kernel<NKV><<<(T_SEQ * NKV * 64) / 256, 256, 0, stream>>>(kb, fcos, fsin);
  transpose_v<<<(T_SEQ * 1024) / 256, 256, 0, stream>>>(vb, vt);

  // 4) attention, 4 chunks of 8 heads (heads 8c..8c+7 -> kv heads 2c + z/4)
  for (int c = 0; c < 4; ++c) {
    gemm_bt<float, false><<<dim3(T_SEQ / 128, T_SEQ / 128, 8), 256, 0, stream>>>(
        qb + c * 1024, C_DIM, 128,
        kb + c * 256, 1024, 128, 2,
        scores, T_SEQ, (long)T_SEQ * T_SEQ, nullptr,
        T_SEQ, T_SEQ, HD);
    softmax_kernel<<<dim3(T_SEQ, 8), 256, 0, stream>>>(scores);
    gemm_bt<unsigned short, false><<<dim3(1, T_SEQ / 128, 8), 256, 0, stream>>>(
        (unsigned short*)scores, 2 * T_SEQ, (long)T_SEQ * 2 * T_SEQ,
        vt + (size_t)c * 2 * HD * T_SEQ, T_SEQ, (long)HD * T_SEQ, 2,
        attn + c * 1024, C_DIM, 128, nullptr,
        T_SEQ, HD, T_SEQ);
  }

  // 5) out = x + attn @ wo^T  (fp32, into d_out == x_mid)
  cvt_kernel<<<(C_DIM * C_DIM) / 1024, 256, 0, stream>>>(wo, Wb);
  gemm_bt<float, true><<<dim3(C_DIM / 128, T_SEQ / 128, 1), 256, 0, stream>>>(
      attn, C_DIM, 0, Wb, C_DIM, 0, 0, out, C_DIM, 0, x, T_SEQ, C_DIM, C_DIM);

  // 6) FFN: xn2 = rmsnorm(out); h = silu(xn2@w1^T) * (xn2@w3^T); out += h@w2^T
  rmsnorm_kernel<<<T_SEQ, 256, 0, stream>>>(out, ln2, xn2);
  cvt_kernel<<<((size_t)HIDDEN * C_DIM) / 1024, 256, 0, stream>>>(w1, Wb);
  gemm_bt<unsigned short, false><<<dim3(HIDDEN / 128, T_SEQ / 128, 1), 256, 0, stream>>>(
      xn2, C_DIM, 0, Wb, C_DIM, 0, 0, g1, HIDDEN, 0, nullptr, T_SEQ, HIDDEN, C_DIM);
  cvt_kernel<<<((size_t)HIDDEN * C_DIM) / 1024, 256, 0, stream>>>(w3, Wb);
  gemm_bt<unsigned short, false><<<dim3(HIDDEN / 128, T_SEQ / 128, 1), 256, 0, stream>>>(
      xn2, C_DIM, 0, Wb, C_DIM, 0, 0, g3, HIDDEN, 0, nullptr, T_SEQ, HIDDEN, C_DIM);
  silu_mul_kernel<<<((size_t)T_SEQ * HIDDEN) / 1024, 256, 0, stream>>>(g1, g3, hb);
  cvt_kernel<<<((size_t)C_DIM * HIDDEN) / 1024, 256, 0, stream>>>(w2, Wb);
  gemm_bt<float, true><<<dim3(C_DIM / 128, T_SEQ / 128, 1), 256, 0, stream>>>(
      hb, HIDDEN, 0, Wb, HIDDEN, 0, 0, out, C_DIM, 0, out, T_SEQ, C_DIM, HIDDEN);
}

// Round 3
// 1787.502 us; speedup vs baseline: 1.3306x; 1.1959x over previous
//
#include <hip/hip_runtime.h>
#include <stdint.h>

#define T_SEQ 2048
#define C_DIM 4096
#define NHEAD 32
#define NKV 8
#define HD 128
#define HIDDEN 11008
#define QKV_W (C_DIM + 2 * NKV * HD)  // 6144

typedef float f32x4 __attribute__((ext_vector_type(4)));
typedef __bf16 bf16x8 __attribute__((ext_vector_type(8)));
typedef __attribute__((address_space(1))) const void* gptr_t;
typedef __attribute__((address_space(3))) void* lptr_t;

__device__ __forceinline__ unsigned short f2bf(float f) {
  unsigned u = __float_as_uint(f);
  u += 0x7fffu + ((u >> 16) & 1u);
  return (unsigned short)(u >> 16);
}
__device__ __forceinline__ float bf2f(unsigned short h) {
  return __uint_as_float(((unsigned)h) << 16);
}

// ---------------------------------------------------------------------------
// bf16 GEMM: C[M,N] = A[M,K] @ B[N,K]^T (+ optional fp32 residual).
// All shapes/strides compile-time (m97 showed runtime dims cost ~VALU issue).
// 128x128 tile, BK=64, 4 waves, 4x4 MFMA 16x16x32/wave, global_load_lds w=16.
// XOR swizzle (verified round 2: SQ_LDS_BANK_CONFLICT 6.76e7 -> 0): LDS chunk
// p of row r holds global chunk p^(r&7); applied on the global source address
// at staging (LDS dest of global_load_lds is fixed at base+lane*16).
// Batched over blockIdx.z; B-stride applies to (z>>BZSH).
// ---------------------------------------------------------------------------
template <typename OutT, bool RESID, int LDA, int LDB, int LDC, int K,
          long SAZ, long SBZ, int BZSH, long SCZ>
__global__ __launch_bounds__(256) void gemm_bt(
    const unsigned short* __restrict__ A, const unsigned short* __restrict__ B,
    OutT* __restrict__ C, const float* __restrict__ R)
{
  const int z = blockIdx.z;
  A += (long)z * SAZ;
  B += (long)(z >> BZSH) * SBZ;
  C += (long)z * SCZ;
  const float* Rz = RESID ? (R + (long)z * SCZ) : nullptr;

  __shared__ unsigned short lA[128 * 64];
  __shared__ unsigned short lB[128 * 64];

  const int t     = threadIdx.x;
  const int lane  = t & 63;
  const int srow  = t >> 3;                          // 0..31
  const int scolL = (t & 7) << 3;                    // LDS chunk (fixed by HW)
  const int scolG = (((t & 7) ^ (srow & 7)) << 3);   // swizzled global chunk
  const int wave  = t >> 6;
  const int wr    = (wave >> 1) << 6;
  const int wc    = (wave & 1) << 6;
  const int m16   = lane & 15;
  const int quad  = lane >> 4;
  const int rl    = lane & 7;                        // fragment row & 7
  const int c0    = ((quad ^ rl) << 3);              // kk=0 swizzled column
  const int c1    = (((4 + quad) ^ rl) << 3);        // kk=32 swizzled column

  const long tileM = (long)blockIdx.y * 128;
  const long tileN = (long)blockIdx.x * 128;

  f32x4 acc[4][4] = {};

  const unsigned short* Aptr = A + (tileM + srow) * LDA + scolG;
  const unsigned short* Bptr = B + (tileN + srow) * LDB + scolG;

  for (int k0 = 0; k0 < K; k0 += 64) {
#pragma unroll
    for (int s = 0; s < 4; ++s) {
      __builtin_amdgcn_global_load_lds((gptr_t)(Aptr + s * 32 * LDA),
                                       (lptr_t)&lA[(s * 32 + srow) * 64 + scolL], 16, 0, 0);
      __builtin_amdgcn_global_load_lds((gptr_t)(Bptr + s * 32 * LDB),
                                       (lptr_t)&lB[(s * 32 + srow) * 64 + scolL], 16, 0, 0);
    }
    Aptr += 64;
    Bptr += 64;
    __syncthreads();
    {
      bf16x8 af[4], bfr[4];
#pragma unroll
      for (int i = 0; i < 4; ++i)
        af[i] = *(const bf16x8*)&lA[(wr + i * 16 + m16) * 64 + c0];
#pragma unroll
      for (int j = 0; j < 4; ++j)
        bfr[j] = *(const bf16x8*)&lB[(wc + j * 16 + m16) * 64 + c0];
#pragma unroll
      for (int i = 0; i < 4; ++i)
#pragma unroll
        for (int j = 0; j < 4; ++j)
          acc[i][j] = __builtin_amdgcn_mfma_f32_16x16x32_bf16(af[i], bfr[j], acc[i][j], 0, 0, 0);
    }
    {
      bf16x8 af[4], bfr[4];
#pragma unroll
      for (int i = 0; i < 4; ++i)
        af[i] = *(const bf16x8*)&lA[(wr + i * 16 + m16) * 64 + c1];
#pragma unroll
      for (int j = 0; j < 4; ++j)
        bfr[j] = *(const bf16x8*)&lB[(wc + j * 16 + m16) * 64 + c1];
#pragma unroll
      for (int i = 0; i < 4; ++i)
#pragma unroll
        for (int j = 0; j < 4; ++j)
          acc[i][j] = __builtin_amdgcn_mfma_f32_16x16x32_bf16(af[i], bfr[j], acc[i][j], 0, 0, 0);
    }
    __syncthreads();
  }

  // C/D layout (verified m89/m91): col = lane&15, row = (lane>>4)*4 + reg
#pragma unroll
  for (int i = 0; i < 4; ++i) {
#pragma unroll
    for (int j = 0; j < 4; ++j) {
      const long row = tileM + wr + i * 16 + quad * 4;
      const long col = tileN + wc + j * 16 + m16;
#pragma unroll
      for (int r = 0; r < 4; ++r) {
        const long off = (row + r) * (long)LDC + col;
        float v = acc[i][j][r];
        if constexpr (RESID) v += Rz[off];
        if constexpr (sizeof(OutT) == 2) C[off] = f2bf(v);
        else                             C[off] = v;
      }
    }
  }
}

// ---------------------------------------------------------------------------
__global__ __launch_bounds__(256) void rmsnorm_kernel(
    const float* __restrict__ x, const float* __restrict__ w,
    unsigned short* __restrict__ out)
{
  const int row = blockIdx.x;
  const int t = threadIdx.x;
  const float4* xr = (const float4*)(x + (long)row * C_DIM);
  float4 xv[4];
  float s = 0.f;
#pragma unroll
  for (int i = 0; i < 4; ++i) {
    float4 a = xr[t * 4 + i];
    xv[i] = a;
    s += a.x * a.x + a.y * a.y + a.z * a.z + a.w * a.w;
  }
#pragma unroll
  for (int off = 32; off > 0; off >>= 1) s += __shfl_down(s, off);
  __shared__ float red[4];
  if ((t & 63) == 0) red[t >> 6] = s;
  __syncthreads();
  const float inv = rsqrtf((red[0] + red[1] + red[2] + red[3]) * (1.f / C_DIM) + 1e-6f);
  const float4* wr4 = (const float4*)w;
  ushort4* o = (ushort4*)(out + (long)row * C_DIM);
#pragma unroll
  for (int i = 0; i < 4; ++i) {
    float4 a = xv[i];
    float4 ww = wr4[t * 4 + i];
    ushort4 r;
    r.x = f2bf(a.x * inv * ww.x); r.y = f2bf(a.y * inv * ww.y);
    r.z = f2bf(a.z * inv * ww.z); r.w = f2bf(a.w * inv * ww.w);
    o[t * 4 + i] = r;
  }
}

// fp32 -> bf16, 4 elements/thread, grid exact (n % 1024 == 0)
__global__ __launch_bounds__(256) void cvt_kernel(
    const float* __restrict__ in, unsigned short* __restrict__ out)
{
  const long i = (long)blockIdx.x * 256 + threadIdx.x;
  float4 f = ((const float4*)in)[i];
  ushort4 r;
  r.x = f2bf(f.x); r.y = f2bf(f.y); r.z = f2bf(f.z); r.w = f2bf(f.w);
  ((ushort4*)out)[i] = r;
}

// RoPE over qkvb rows (row stride QKV_W), head columns start at COFF
template <int NHd, int COFF>
__global__ __launch_bounds__(256) void rope_kernel(
    unsigned short* tq, const float* __restrict__ cp, const float* __restrict__ sp)
{
  constexpr int SH = (NHd == 32) ? 5 : 3;
  const long idx = (long)blockIdx.x * 256 + threadIdx.x;  // over T*NHd*64
  const int i = (int)(idx & 63);
  const long rest = idx >> 6;
  const int h = (int)(rest & (NHd - 1));
  const int t = (int)(rest >> SH);
  const long base = (long)t * QKV_W + COFF + h * HD + 2 * i;
  const float re = bf2f(tq[base]);
  const float im = bf2f(tq[base + 1]);
  const float c = cp[t * 64 + i];
  const float s = sp[t * 64 + i];
  tq[base]     = f2bf(re * c - im * s);
  tq[base + 1] = f2bf(re * s + im * c);
}

// vt[kvd][t] = qkvb[t][5120 + kvd]   (kvd in [0,1024), t in [0,2048))
__global__ __launch_bounds__(256) void transpose_v(
    const unsigned short* __restrict__ qkvb, unsigned short* __restrict__ vt)
{
  const long idx = (long)blockIdx.x * 256 + threadIdx.x;
  const int t = (int)(idx & 2047);
  const int kvd = (int)(idx >> 11);
  vt[idx] = qkvb[(long)t * QKV_W + (C_DIM + NKV * HD) + kvd];
}

// In-place causal softmax on bf16 row (len 2048). scale = 1/sqrt(128).
__global__ __launch_bounds__(256) void softmax_bf16(unsigned short* scores)
{
  const int q = blockIdx.x;
  const long z = blockIdx.y;
  unsigned short* row = scores + (z * T_SEQ + q) * (long)T_SEQ;
  const int t = threadIdx.x;
  const int base = t * 8;
  ushort4 a4 = ((const ushort4*)row)[t * 2];
  ushort4 b4 = ((const ushort4*)row)[t * 2 + 1];
  float v[8] = {bf2f(a4.x), bf2f(a4.y), bf2f(a4.z), bf2f(a4.w),
                bf2f(b4.x), bf2f(b4.y), bf2f(b4.z), bf2f(b4.w)};
  const float scale = 0.08838834764831845f;
  float mx = -INFINITY;
#pragma unroll
  for (int j = 0; j < 8; ++j) {
    v[j] = (base + j <= q) ? v[j] * scale : -INFINITY;
    mx = fmaxf(mx, v[j]);
  }
#pragma unroll
  for (int off = 32; off > 0; off >>= 1) mx = fmaxf(mx, __shfl_down(mx, off));
  __shared__ float redm[4], reds[4];
  if ((t & 63) == 0) redm[t >> 6] = mx;
  __syncthreads();
  mx = fmaxf(fmaxf(redm[0], redm[1]), fmaxf(redm[2], redm[3]));
  float s = 0.f;
#pragma unroll
  for (int j = 0; j < 8; ++j) {
    float e = (base + j <= q) ? __expf(v[j] - mx) : 0.f;
    v[j] = e;
    s += e;
  }
#pragma unroll
  for (int off = 32; off > 0; off >>= 1) s += __shfl_down(s, off);
  if ((t & 63) == 0) reds[t >> 6] = s;
  __syncthreads();
  s = reds[0] + reds[1] + reds[2] + reds[3];
  const float inv = 1.f / s;
  ushort4 o0, o1;
  o0.x = f2bf(v[0] * inv); o0.y = f2bf(v[1] * inv);
  o0.z = f2bf(v[2] * inv); o0.w = f2bf(v[3] * inv);
  o1.x = f2bf(v[4] * inv); o1.y = f2bf(v[5] * inv);
  o1.z = f2bf(v[6] * inv); o1.w = f2bf(v[7] * inv);
  ((ushort4*)row)[t * 2]     = o0;
  ((ushort4*)row)[t * 2 + 1] = o1;
}

// h = silu(g1) * g3, 4 elements/thread
__global__ __launch_bounds__(256) void silu_mul_kernel(
    const unsigned short* __restrict__ g1, const unsigned short* __restrict__ g3,
    unsigned short* __restrict__ h)
{
  const long i = (long)blockIdx.x * 256 + threadIdx.x;
  ushort4 a4 = ((const ushort4*)g1)[i];
  ushort4 b4 = ((const ushort4*)g3)[i];
  ushort4 r;
  { float a = bf2f(a4.x), b = bf2f(b4.x); r.x = f2bf(a / (1.f + __expf(-a)) * b); }
  { float a = bf2f(a4.y), b = bf2f(b4.y); r.y = f2bf(a / (1.f + __expf(-a)) * b); }
  { float a = bf2f(a4.z), b = bf2f(b4.z); r.z = f2bf(a / (1.f + __expf(-a)) * b); }
  { float a = bf2f(a4.w), b = bf2f(b4.w); r.w = f2bf(a / (1.f + __expf(-a)) * b); }
  ((ushort4*)h)[i] = r;
}

// ---------------------------------------------------------------------------
extern "C" void kernel_launch(void* const* d_in, const int* in_sizes, int n_in,
                              void* d_out, int out_size, void* d_ws, size_t ws_size,
                              hipStream_t stream) {
  const float* x    = (const float*)d_in[0];
  const float* fcos = (const float*)d_in[2];
  const float* fsin = (const float*)d_in[3];
  const float* wq   = (const float*)d_in[5];
  const float* wk   = (const float*)d_in[6];
  const float* wv   = (const float*)d_in[7];
  const float* wo   = (const float*)d_in[8];
  const float* w1   = (const float*)d_in[9];
  const float* w2   = (const float*)d_in[10];
  const float* w3   = (const float*)d_in[11];
  const float* ln1  = (const float*)d_in[12];
  const float* ln2  = (const float*)d_in[13];
  float* out = (float*)d_out;  // also x_mid (attention residual output)

  char* p = (char*)d_ws;
  auto alloc = [&](size_t bytes) { char* r = p; p += (bytes + 255) & ~(size_t)255; return r; };
  unsigned short* Wb   = (unsigned short*)alloc((size_t)HIDDEN * C_DIM * 2);  // 90.2 MB
  unsigned short* xn   = (unsigned short*)alloc((size_t)T_SEQ * C_DIM * 2);
  unsigned short* qkvb = (unsigned short*)alloc((size_t)T_SEQ * QKV_W * 2);   // q|k|v packed per row
  unsigned short* vt   = (unsigned short*)alloc((size_t)T_SEQ * 1024 * 2);
  unsigned short* attn = (unsigned short*)alloc((size_t)T_SEQ * C_DIM * 2);
  const size_t scoresAllB = (size_t)NHEAD * T_SEQ * T_SEQ * 2;   // 268 MB (bf16, all heads)
  const size_t scoresChkB = (size_t)8 * T_SEQ * T_SEQ * 2;       // 67 MB
  const size_t ffnB = (size_t)T_SEQ * C_DIM * 2 + 3ULL * T_SEQ * HIDDEN * 2;  // 152 MB
  const size_t usedSoFar = (size_t)(p - (char*)d_ws);
  const bool allHeads = ws_size >= usedSoFar + (scoresAllB > ffnB ? scoresAllB : ffnB) + 1024;
  char* regC = alloc((allHeads ? scoresAllB : (scoresChkB > ffnB ? scoresChkB : ffnB)) > ffnB
                         ? (allHeads ? scoresAllB : (scoresChkB > ffnB ? scoresChkB : ffnB))
                         : ffnB);
  unsigned short* scores = (unsigned short*)regC;               // attention phase (bf16)
  unsigned short* xn2 = (unsigned short*)regC;                  // FFN phase
  unsigned short* g1  = (unsigned short*)(regC + (size_t)T_SEQ * C_DIM * 2);
  unsigned short* g3  = (unsigned short*)(regC + (size_t)T_SEQ * C_DIM * 2 + (size_t)T_SEQ * HIDDEN * 2);
  unsigned short* hb  = (unsigned short*)(regC + (size_t)T_SEQ * C_DIM * 2 + 2ULL * T_SEQ * HIDDEN * 2);

  constexpr long TT = (long)T_SEQ * T_SEQ;

  // 1) xn = rmsnorm(x)
  rmsnorm_kernel<<<T_SEQ, 256, 0, stream>>>(x, ln1, xn);

  // 2) fused QKV projection: Wb rows = [wq(4096) | wk(1024) | wv(1024)]
  cvt_kernel<<<(C_DIM * C_DIM) / 1024, 256, 0, stream>>>(wq, Wb);
  cvt_kernel<<<(NKV * HD * C_DIM) / 1024, 256, 0, stream>>>(wk, Wb + (size_t)C_DIM * C_DIM);
  cvt_kernel<<<(NKV * HD * C_DIM) / 1024, 256, 0, stream>>>(wv, Wb + (size_t)(C_DIM + NKV * HD) * C_DIM);
  gemm_bt<unsigned short, false, C_DIM, C_DIM, QKV_W, C_DIM, 0, 0, 0, 0>
      <<<dim3(QKV_W / 128, T_SEQ / 128, 1), 256, 0, stream>>>(xn, Wb, qkvb, nullptr);

  // 3) RoPE q (cols 0..4095) and k (cols 4096..5119); transpose v
  rope_kernel<NHEAD, 0><<<(T_SEQ * NHEAD * 64) / 256, 256, 0, stream>>>(qkvb, fcos, fsin);
  rope_kernel<NKV, C_DIM><<<(T_SEQ * NKV * 64) / 256, 256, 0, stream>>>(qkvb, fcos, fsin);
  transpose_v<<<(T_SEQ * 1024) / 256, 256, 0, stream>>>(qkvb, vt);

  // 4) attention (bf16 scores end-to-end)
  if (allHeads) {
    gemm_bt<unsigned short, false, QKV_W, QKV_W, T_SEQ, HD, HD, HD, 2, TT>
        <<<dim3(T_SEQ / 128, T_SEQ / 128, NHEAD), 256, 0, stream>>>(
            qkvb, qkvb + C_DIM, scores, nullptr);
    softmax_bf16<<<dim3(T_SEQ, NHEAD), 256, 0, stream>>>(scores);
    gemm_bt<unsigned short, false, T_SEQ, T_SEQ, C_DIM, T_SEQ, TT, (long)HD * T_SEQ, 2, HD>
        <<<dim3(1, T_SEQ / 128, NHEAD), 256, 0, stream>>>(scores, vt, attn, nullptr);
  } else {
    for (int c = 0; c < 4; ++c) {
      gemm_bt<unsigned short, false, QKV_W, QKV_W, T_SEQ, HD, HD, HD, 2, TT>
          <<<dim3(T_SEQ / 128, T_SEQ / 128, 8), 256, 0, stream>>>(
              qkvb + c * 1024, qkvb + C_DIM + c * 256, scores, nullptr);
      softmax_bf16<<<dim3(T_SEQ, 8), 256, 0, stream>>>(scores);
      gemm_bt<unsigned short, false, T_SEQ, T_SEQ, C_DIM, T_SEQ, TT, (long)HD * T_SEQ, 2, HD>
          <<<dim3(1, T_SEQ / 128, 8), 256, 0, stream>>>(
              scores, vt + (size_t)c * 256 * T_SEQ, attn + c * 1024, nullptr);
    }
  }

  // 5) out = x + attn @ wo^T
  cvt_kernel<<<(C_DIM * C_DIM) / 1024, 256, 0, stream>>>(wo, Wb);
  gemm_bt<float, true, C_DIM, C_DIM, C_DIM, C_DIM, 0, 0, 0, 0>
      <<<dim3(C_DIM / 128, T_SEQ / 128, 1), 256, 0, stream>>>(attn, Wb, out, x);

  // 6) FFN
  rmsnorm_kernel<<<T_SEQ, 256, 0, stream>>>(out, ln2, xn2);
  cvt_kernel<<<((size_t)HIDDEN * C_DIM) / 1024, 256, 0, stream>>>(w1, Wb);
  gemm_bt<unsigned short, false, C_DIM, C_DIM, HIDDEN, C_DIM, 0, 0, 0, 0>
      <<<dim3(HIDDEN / 128, T_SEQ / 128, 1), 256, 0, stream>>>(xn2, Wb, g1, nullptr);
  cvt_kernel<<<((size_t)HIDDEN * C_DIM) / 1024, 256, 0, stream>>>(w3, Wb);
  gemm_bt<unsigned short, false, C_DIM, C_DIM, HIDDEN, C_DIM, 0, 0, 0, 0>
      <<<dim3(HIDDEN / 128, T_SEQ / 128, 1), 256, 0, stream>>>(xn2, Wb, g3, nullptr);
  silu_mul_kernel<<<((size_t)T_SEQ * HIDDEN) / 1024, 256, 0, stream>>>(g1, g3, hb);
  cvt_kernel<<<((size_t)C_DIM * HIDDEN) / 1024, 256, 0, stream>>>(w2, Wb);
  gemm_bt<float, true, HIDDEN, HIDDEN, C_DIM, HIDDEN, 0, 0, 0, 0>
      <<<dim3(C_DIM / 128, T_SEQ / 128, 1), 256, 0, stream>>>(hb, Wb, out, out);
}